// Round 10
// baseline (13.514 us; speedup 1.0000x reference)
//
#include <hip/hip_runtime.h>

// Fused quantum-transformer block, v10: two independent 4-wave blocks per CU.
// 512 blocks x 256 threads (2 blocks/CU), 2 tokens/wave, 8 tokens/block.
// Both GEMMs on the matrix pipe with ALL 4 waves active (M=16, token rows
// 8-15 unused garbage -- MFMA rows are independent, outputs never read).
// Two co-resident blocks interleave their serial chains (latency hiding).
//
// Closed-form circuit (verified round 1): OPS = ry(0,t0) rx(3,t1) rz(5,t2)
// cx(1,4) ry(6,t3) rx(2,t4) cx(0,7) rz(4,t5) on RX(a_w)-encoded product state.
//   z0 = cos(t0) cos(a0)          z4 = cos(a1) cos(a4)
//   z1 = cos(a1)                  z5 = cos(a5)
//   z2 = cos(a2 + t4)             z6 = cos(t3) cos(a6)
//   z3 = cos(a3 + t1)             z7 = cos(t0) cos(a0) cos(a7)
//
// LDS (~65 KB/block, 2 blocks/CU = 130 KB < 160 KB):
//   sWct[e][q] f16 pad 72 : Wc transposed                        9.2 KB
//   sW1 [j]    int4       : (pk(W1[k][j],W1[k+4][j]) k=0..3)     4 KB
//   sW2t[e][k] f16 pad 264: W2 transposed                       33 KB
//   sZ  [16][72]  f16     : circuit expectations (rows 0-7 valid) 2.3 KB
//   sA  [16][66]  f32     : attn GEMM out                         4.2 KB
//   sH  [16][264] f16     : ffn1 activations (rows 0-7 valid)     8.3 KB
//   sO  [16][66]  f32     : ffn2 GEMM out                         4.2 KB

typedef _Float16 h2f   __attribute__((ext_vector_type(2)));
typedef _Float16 f16x8 __attribute__((ext_vector_type(8)));
typedef float    f32x4 __attribute__((ext_vector_type(4)));

__device__ __forceinline__ int pk(float a, float b) {
    return __builtin_bit_cast(int, __builtin_amdgcn_cvt_pkrtz(a, b));
}
__device__ __forceinline__ float fdot2i(int a, int b, float c) {
    return __builtin_amdgcn_fdot2(__builtin_bit_cast(h2f, a),
                                  __builtin_bit_cast(h2f, b), c, false);
}
__device__ __forceinline__ float rl_f(float v, int l) {
    return __int_as_float(__builtin_amdgcn_readlane(__float_as_int(v), l));
}
__device__ __forceinline__ void wave_sum2(float& a, float& b) {
#pragma unroll
    for (int m = 32; m > 0; m >>= 1) {
        a += __shfl_xor(a, m, 64);
        b += __shfl_xor(b, m, 64);
    }
}

__global__ __launch_bounds__(256, 2)
void qtb_fused10(const float* __restrict__ x,
                 const float* __restrict__ th_a,
                 const float* __restrict__ Wc,
                 const float* __restrict__ bc,
                 const float* __restrict__ g1,
                 const float* __restrict__ be1,
                 const float* __restrict__ th_f,
                 const float* __restrict__ W1,
                 const float* __restrict__ b1,
                 const float* __restrict__ W2,
                 const float* __restrict__ b2,
                 const float* __restrict__ g2,
                 const float* __restrict__ be2,
                 float* __restrict__ out)
{
    __shared__ __align__(16) _Float16  sWct[64][72];     //  9.2 KB
    __shared__ __align__(16) int4      sW1[256];         //  4 KB
    __shared__ __align__(16) _Float16  sW2t[64][264];    // 33 KB
    __shared__ __align__(16) _Float16  sZ[16][72];       //  2.3 KB
    __shared__ __align__(16) float     sA[16][66];       //  4.2 KB
    __shared__ __align__(16) _Float16  sH[16][264];      //  8.3 KB
    __shared__ __align__(16) float     sO[16][66];       //  4.2 KB

    const int tid  = threadIdx.x;                 // 0..255
    const int lane = tid & 63;
    const int wv   = tid >> 6;                    // 0..3
    const int w    = lane & 7;
    const int gb   = lane & ~7;
    const int tok0 = (blockIdx.x * 4 + wv) * 2;   // 2 tokens per wave
    const int tl   = wv * 2;                      // local token row 0..7

    // ---- stage weights into LDS (float4 global loads) ----
    // W2 transposed to f16 [e][k]: 512 tasks over 256 threads (2 each)
#pragma unroll
    for (int s = 0; s < 2; ++s) {
        int task = tid + 256 * s;
        int k0 = (task & 31) * 8;        // 0..248
        int e0 = (task >> 5) * 4;        // 0..60
        float4 r[8];
#pragma unroll
        for (int i = 0; i < 8; ++i)
            r[i] = *(const float4*)&W2[(k0 + i) * 64 + e0];
        const float* f = (const float*)r;   // f[i*4 + j] = W2[k0+i][e0+j]
#pragma unroll
        for (int j = 0; j < 4; ++j)
            *(int4*)&sW2t[e0 + j][k0] =
                make_int4(pk(f[0 * 4 + j], f[1 * 4 + j]),
                          pk(f[2 * 4 + j], f[3 * 4 + j]),
                          pk(f[4 * 4 + j], f[5 * 4 + j]),
                          pk(f[6 * 4 + j], f[7 * 4 + j]));
    }
    // Wc transposed to f16 [e][q]: threads 0..127
    if (tid < 128) {
        int q0 = (tid & 7) * 8;          // 0..56
        int e0 = (tid >> 3) * 4;         // 0..60
        float4 r[8];
#pragma unroll
        for (int i = 0; i < 8; ++i)
            r[i] = *(const float4*)&Wc[(q0 + i) * 64 + e0];
        const float* f = (const float*)r;   // f[i*4 + j] = Wc[q0+i][e0+j]
#pragma unroll
        for (int j = 0; j < 4; ++j)
            *(int4*)&sWct[e0 + j][q0] =
                make_int4(pk(f[0 * 4 + j], f[1 * 4 + j]),
                          pk(f[2 * 4 + j], f[3 * 4 + j]),
                          pk(f[4 * 4 + j], f[5 * 4 + j]),
                          pk(f[6 * 4 + j], f[7 * 4 + j]));
    } else if (tid < 192) {
        // W1: threads 128..191, packed pairs (k, k+4)
        int j0 = (tid - 128) * 4;
        float4 r[8];
#pragma unroll
        for (int k = 0; k < 8; ++k) r[k] = *(const float4*)&W1[k * 256 + j0];
        const float* f = (const float*)r;   // f[k*4 + j]
#pragma unroll
        for (int j = 0; j < 4; ++j)
            sW1[j0 + j] = make_int4(pk(f[0 * 4 + j], f[4 * 4 + j]),
                                    pk(f[1 * 4 + j], f[5 * 4 + j]),
                                    pk(f[2 * 4 + j], f[6 * 4 + j]),
                                    pk(f[3 * 4 + j], f[7 * 4 + j]));
    }

    // independent global loads issued while staging is in flight
    float xr[2];
#pragma unroll
    for (int t = 0; t < 2; ++t) xr[t] = x[(tok0 + t) * 64 + lane];

    const float C0a = __cosf(th_a[0]);
    const float T1a = th_a[1];
    const float C3a = __cosf(th_a[3]);
    const float T4a = th_a[4];
    const float C0f = __cosf(th_f[0]);
    const float T1f = th_f[1];
    const float C3f = __cosf(th_f[3]);
    const float T4f = th_f[4];

    const float bcL = bc[lane], g1L = g1[lane], be1L = be1[lane];
    const float b2L = b2[lane], g2L = g2[lane], be2L = be2[lane];
    float b1L[4];
#pragma unroll
    for (int r = 0; r < 4; ++r) b1L[r] = b1[r * 64 + lane];

    // ---- quantum attention expectations -> sZ (f16, rows 0..7) ----
    const float dA = (w == 2) ? T4a : ((w == 3) ? T1a : 0.0f);
#pragma unroll
    for (int t = 0; t < 2; ++t) {
        float c  = __cosf(xr[t] + dA);
        float c0 = __shfl(c, gb, 64);       // cos(a0) of this 8-group
        float c1 = __shfl(c, gb + 1, 64);   // cos(a1)
        float zz = c * ((w == 0) ? C0a : ((w == 6) ? C3a : 1.0f));
        if (w == 4) zz = c * c1;
        if (w == 7) zz = C0a * c0 * c;
        sZ[tl + t][lane] = (_Float16)zz;
    }

    __syncthreads();   // barrier 1: staging + sZ complete

    const int col = lane & 15;
    const int kg  = lane >> 4;

    // ---- attn GEMM: M=16 (rows 0-7 valid) x N=64 x K=64, all 4 waves ----
    {
        f32x4 cacc = {0.0f, 0.0f, 0.0f, 0.0f};
#pragma unroll
        for (int ks = 0; ks < 2; ++ks) {
            f16x8 af = *(const f16x8*)&sZ[col][ks * 32 + kg * 8];
            f16x8 bf = *(const f16x8*)&sWct[wv * 16 + col][ks * 32 + kg * 8];
            cacc = __builtin_amdgcn_mfma_f32_16x16x32_f16(af, bf, cacc, 0, 0, 0);
        }
#pragma unroll
        for (int r = 0; r < 4; ++r)
            sA[kg * 4 + r][wv * 16 + col] = cacc[r];
    }

    __syncthreads();   // barrier 2: sA complete

    // ---- y = LN(x + attn + bc) ----
    float y[2];
#pragma unroll
    for (int t = 0; t < 2; ++t) {
        float v = xr[t] + sA[tl + t][lane] + bcL;
        float s = v, s2 = v * v;
        wave_sum2(s, s2);
        float m   = s * 0.015625f;
        float var = s2 * 0.015625f - m * m;
        y[t] = (v - m) * rsqrtf(var + 1e-5f) * g1L + be1L;
    }

    // ---- ffn quantum gate (y[:, :8]) + h = relu(QF @ W1 + b1) -> sH ----
    int4 w1q[4];
#pragma unroll
    for (int r = 0; r < 4; ++r) w1q[r] = sW1[r * 64 + lane];

    const float dF = (w == 2) ? T4f : ((w == 3) ? T1f : 0.0f);
#pragma unroll
    for (int t = 0; t < 2; ++t) {
        float cy = __cosf(y[t] + dF);        // meaningful on lanes 0..7
        float c0 = rl_f(cy, 0);
        float c1 = rl_f(cy, 1);
        float qz = cy * ((w == 0) ? C0f : ((w == 6) ? C3f : 1.0f));
        if (w == 4) qz = cy * c1;
        if (w == 7) qz = C0f * c0 * cy;
        int qp0 = pk(rl_f(qz, 0), rl_f(qz, 4));   // pairs (k, k+4)
        int qp1 = pk(rl_f(qz, 1), rl_f(qz, 5));
        int qp2 = pk(rl_f(qz, 2), rl_f(qz, 6));
        int qp3 = pk(rl_f(qz, 3), rl_f(qz, 7));
#pragma unroll
        for (int r = 0; r < 4; ++r) {
            float a = b1L[r];
            a = fdot2i(qp0, w1q[r].x, a);
            a = fdot2i(qp1, w1q[r].y, a);
            a = fdot2i(qp2, w1q[r].z, a);
            a = fdot2i(qp3, w1q[r].w, a);
            sH[tl + t][r * 64 + lane] = (_Float16)fmaxf(a, 0.0f);
        }
    }

    __syncthreads();   // barrier 3: sH complete

    // ---- ffn2 GEMM: M=16 (rows 0-7 valid) x N=64 x K=256, all 4 waves ----
    {
        f32x4 cacc = {0.0f, 0.0f, 0.0f, 0.0f};
#pragma unroll
        for (int ks = 0; ks < 8; ++ks) {
            f16x8 af = *(const f16x8*)&sH[col][ks * 32 + kg * 8];
            f16x8 bf = *(const f16x8*)&sW2t[wv * 16 + col][ks * 32 + kg * 8];
            cacc = __builtin_amdgcn_mfma_f32_16x16x32_f16(af, bf, cacc, 0, 0, 0);
        }
#pragma unroll
        for (int r = 0; r < 4; ++r)
            sO[kg * 4 + r][wv * 16 + col] = cacc[r];
    }

    __syncthreads();   // barrier 4: sO complete

    // ---- out = LN(y + ffn2 + b2) ----
#pragma unroll
    for (int t = 0; t < 2; ++t) {
        float v = y[t] + b2L + sO[tl + t][lane];
        float s = v, s2 = v * v;
        wave_sum2(s, s2);
        float m   = s * 0.015625f;
        float var = s2 * 0.015625f - m * m;
        out[(tok0 + t) * 64 + lane] = (v - m) * rsqrtf(var + 1e-5f) * g2L + be2L;
    }
}

extern "C" void kernel_launch(void* const* d_in, const int* in_sizes, int n_in,
                              void* d_out, int out_size, void* d_ws, size_t ws_size,
                              hipStream_t stream)
{
    const float* x   = (const float*)d_in[0];
    const float* at  = (const float*)d_in[1];
    const float* Wc  = (const float*)d_in[2];
    const float* bcp = (const float*)d_in[3];
    const float* g1  = (const float*)d_in[4];
    const float* be1 = (const float*)d_in[5];
    const float* ft  = (const float*)d_in[6];
    const float* W1  = (const float*)d_in[7];
    const float* b1  = (const float*)d_in[8];
    const float* W2  = (const float*)d_in[9];
    const float* b2  = (const float*)d_in[10];
    const float* g2  = (const float*)d_in[11];
    const float* be2 = (const float*)d_in[12];
    float* out = (float*)d_out;

    // 4096 tokens = 512 blocks x 4 waves x 2 tokens; single dispatch,
    // 2 blocks/CU (~65 KB LDS each), 4-wave barriers, overlapping chains.
    qtb_fused10<<<512, 256, 0, stream>>>(x, at, Wc, bcp, g1, be1, ft,
                                         W1, b1, W2, b2, g2, be2, out);
}

// Round 11
// 9.748 us; speedup vs baseline: 1.3864x; 1.3864x over previous
//
#include <hip/hip_runtime.h>

// Fused quantum-transformer block, v11: v9 structure, but NO LDS staging for
// Wc/W2 -- each GEMM wave loads its private B-fragments directly from global
// into registers at kernel entry (2000+ cycles of prefetch slack).
// 256 blocks x 512 threads (1 block/CU, 8 waves, 2 waves/SIMD), 2 tokens/wave.
// attn = Z@Wc via mfma (waves 0-3), ffn2 = H@W2 via mfma (waves 4-7).
//
// Closed-form circuit (verified round 1): OPS = ry(0,t0) rx(3,t1) rz(5,t2)
// cx(1,4) ry(6,t3) rx(2,t4) cx(0,7) rz(4,t5) on RX(a_w)-encoded product state.
//   z0 = cos(t0) cos(a0)          z4 = cos(a1) cos(a4)
//   z1 = cos(a1)                  z5 = cos(a5)
//   z2 = cos(a2 + t4)             z6 = cos(t3) cos(a6)
//   z3 = cos(a3 + t1)             z7 = cos(t0) cos(a0) cos(a7)
//
// LDS (~23 KB):
//   sW1[j] int4        : (pk(W1[k][j],W1[k+4][j]) k=0..3)      4 KB
//   sZ [16][72]  f16   : circuit expectations                  2.3 KB
//   sA [16][66]  f32   : attn GEMM out                         4.2 KB
//   sH [16][264] f16   : ffn1 activations                      8.3 KB
//   sO [16][66]  f32   : ffn2 GEMM out                         4.2 KB

typedef _Float16 h2f   __attribute__((ext_vector_type(2)));
typedef _Float16 f16x8 __attribute__((ext_vector_type(8)));
typedef float    f32x4 __attribute__((ext_vector_type(4)));
typedef int      i32x4 __attribute__((ext_vector_type(4)));

__device__ __forceinline__ int pk(float a, float b) {
    return __builtin_bit_cast(int, __builtin_amdgcn_cvt_pkrtz(a, b));
}
__device__ __forceinline__ float fdot2i(int a, int b, float c) {
    return __builtin_amdgcn_fdot2(__builtin_bit_cast(h2f, a),
                                  __builtin_bit_cast(h2f, b), c, false);
}
__device__ __forceinline__ float rl_f(float v, int l) {
    return __int_as_float(__builtin_amdgcn_readlane(__float_as_int(v), l));
}
__device__ __forceinline__ f16x8 pack8(const float (&v)[8]) {
    i32x4 p;
    p.x = pk(v[0], v[1]);
    p.y = pk(v[2], v[3]);
    p.z = pk(v[4], v[5]);
    p.w = pk(v[6], v[7]);
    return __builtin_bit_cast(f16x8, p);
}
__device__ __forceinline__ void wave_sum2(float& a, float& b) {
#pragma unroll
    for (int m = 32; m > 0; m >>= 1) {
        a += __shfl_xor(a, m, 64);
        b += __shfl_xor(b, m, 64);
    }
}

__global__ __launch_bounds__(512, 2)
void qtb_fused11(const float* __restrict__ x,
                 const float* __restrict__ th_a,
                 const float* __restrict__ Wc,
                 const float* __restrict__ bc,
                 const float* __restrict__ g1,
                 const float* __restrict__ be1,
                 const float* __restrict__ th_f,
                 const float* __restrict__ W1,
                 const float* __restrict__ b1,
                 const float* __restrict__ W2,
                 const float* __restrict__ b2,
                 const float* __restrict__ g2,
                 const float* __restrict__ be2,
                 float* __restrict__ out)
{
    __shared__ __align__(16) int4      sW1[256];       //  4 KB
    __shared__ __align__(16) _Float16  sZ[16][72];     //  2.3 KB
    __shared__ __align__(16) float     sA[16][66];     //  4.2 KB
    __shared__ __align__(16) _Float16  sH[16][264];    //  8.3 KB
    __shared__ __align__(16) float     sO[16][66];     //  4.2 KB

    const int tid  = threadIdx.x;                 // 0..511
    const int lane = tid & 63;
    const int wv   = tid >> 6;                    // 0..7
    const int w    = lane & 7;
    const int gb   = lane & ~7;
    const int tok0 = (blockIdx.x * 8 + wv) * 2;   // 2 tokens per wave
    const int tl   = wv * 2;                      // local token row
    const int col  = lane & 15;                   // MFMA col index
    const int kg   = lane >> 4;                   // MFMA k-group

    // ---- early global loads: x + this wave's private B-fragments ----
    float xr[2];
#pragma unroll
    for (int t = 0; t < 2; ++t) xr[t] = x[(tok0 + t) * 64 + lane];

    // B[n=e][k] fragments: 8 dword loads per fragment, stride 64 floats.
    // Lanes 0-15 hit 64B contiguous; issued here, consumed post-barrier.
    float bfa[2][8];    // waves 0-3: Wc columns wv*16+col
    float bff[8][8];    // waves 4-7: W2 columns (wv-4)*16+col
    if (wv < 4) {
        const float* base = Wc + wv * 16 + col;
#pragma unroll
        for (int ks = 0; ks < 2; ++ks)
#pragma unroll
            for (int i = 0; i < 8; ++i)
                bfa[ks][i] = base[(ks * 32 + kg * 8 + i) * 64];
    } else {
        const float* base = W2 + (wv - 4) * 16 + col;
#pragma unroll
        for (int ks = 0; ks < 8; ++ks)
#pragma unroll
            for (int i = 0; i < 8; ++i)
                bff[ks][i] = base[(ks * 32 + kg * 8 + i) * 64];
    }

    // ---- W1 staging (only remaining LDS staging): threads 0..63 ----
    if (tid < 64) {
        int j0 = tid * 4;
        float4 r[8];
#pragma unroll
        for (int k = 0; k < 8; ++k) r[k] = *(const float4*)&W1[k * 256 + j0];
        const float* f = (const float*)r;   // f[k*4 + j]
#pragma unroll
        for (int j = 0; j < 4; ++j)
            sW1[j0 + j] = make_int4(pk(f[0 * 4 + j], f[4 * 4 + j]),
                                    pk(f[1 * 4 + j], f[5 * 4 + j]),
                                    pk(f[2 * 4 + j], f[6 * 4 + j]),
                                    pk(f[3 * 4 + j], f[7 * 4 + j]));
    }

    const float C0a = __cosf(th_a[0]);
    const float T1a = th_a[1];
    const float C3a = __cosf(th_a[3]);
    const float T4a = th_a[4];
    const float C0f = __cosf(th_f[0]);
    const float T1f = th_f[1];
    const float C3f = __cosf(th_f[3]);
    const float T4f = th_f[4];

    const float bcL = bc[lane], g1L = g1[lane], be1L = be1[lane];
    const float b2L = b2[lane], g2L = g2[lane], be2L = be2[lane];
    float b1L[4];
#pragma unroll
    for (int r = 0; r < 4; ++r) b1L[r] = b1[r * 64 + lane];

    // ---- quantum attention expectations -> sZ (f16) ----
    const float dA = (w == 2) ? T4a : ((w == 3) ? T1a : 0.0f);
#pragma unroll
    for (int t = 0; t < 2; ++t) {
        float c  = __cosf(xr[t] + dA);
        float c0 = __shfl(c, gb, 64);       // cos(a0) of this 8-group
        float c1 = __shfl(c, gb + 1, 64);   // cos(a1)
        float zz = c * ((w == 0) ? C0a : ((w == 6) ? C3a : 1.0f));
        if (w == 4) zz = c * c1;
        if (w == 7) zz = C0a * c0 * c;
        sZ[tl + t][lane] = (_Float16)zz;
    }

    // ---- convert B-fragments to f16 (loads landed long ago) ----
    f16x8 bfrag[8];
    if (wv < 4) {
#pragma unroll
        for (int ks = 0; ks < 2; ++ks) bfrag[ks] = pack8(bfa[ks]);
    } else {
#pragma unroll
        for (int ks = 0; ks < 8; ++ks) bfrag[ks] = pack8(bff[ks]);
    }

    __syncthreads();   // barrier 1: sZ + sW1 complete

    // ---- attn GEMM: A=sZ[16][64], B=bfrag, waves 0..3, 2 MFMA ----
    if (wv < 4) {
        f32x4 cacc = {0.0f, 0.0f, 0.0f, 0.0f};
#pragma unroll
        for (int ks = 0; ks < 2; ++ks) {
            f16x8 af = *(const f16x8*)&sZ[col][ks * 32 + kg * 8];
            cacc = __builtin_amdgcn_mfma_f32_16x16x32_f16(af, bfrag[ks], cacc, 0, 0, 0);
        }
#pragma unroll
        for (int r = 0; r < 4; ++r)
            sA[kg * 4 + r][wv * 16 + col] = cacc[r];
    }

    __syncthreads();   // barrier 2: sA complete

    // ---- y = LN(x + attn + bc) ----
    float y[2];
#pragma unroll
    for (int t = 0; t < 2; ++t) {
        float v = xr[t] + sA[tl + t][lane] + bcL;
        float s = v, s2 = v * v;
        wave_sum2(s, s2);
        float m   = s * 0.015625f;
        float var = s2 * 0.015625f - m * m;
        y[t] = (v - m) * rsqrtf(var + 1e-5f) * g1L + be1L;
    }

    // ---- ffn quantum gate (y[:, :8]) + h = relu(QF @ W1 + b1) -> sH ----
    int4 w1q[4];
#pragma unroll
    for (int r = 0; r < 4; ++r) w1q[r] = sW1[r * 64 + lane];

    const float dF = (w == 2) ? T4f : ((w == 3) ? T1f : 0.0f);
#pragma unroll
    for (int t = 0; t < 2; ++t) {
        float cy = __cosf(y[t] + dF);        // meaningful on lanes 0..7
        float c0 = rl_f(cy, 0);
        float c1 = rl_f(cy, 1);
        float qz = cy * ((w == 0) ? C0f : ((w == 6) ? C3f : 1.0f));
        if (w == 4) qz = cy * c1;
        if (w == 7) qz = C0f * c0 * cy;
        int qp0 = pk(rl_f(qz, 0), rl_f(qz, 4));   // pairs (k, k+4)
        int qp1 = pk(rl_f(qz, 1), rl_f(qz, 5));
        int qp2 = pk(rl_f(qz, 2), rl_f(qz, 6));
        int qp3 = pk(rl_f(qz, 3), rl_f(qz, 7));
#pragma unroll
        for (int r = 0; r < 4; ++r) {
            float a = b1L[r];
            a = fdot2i(qp0, w1q[r].x, a);
            a = fdot2i(qp1, w1q[r].y, a);
            a = fdot2i(qp2, w1q[r].z, a);
            a = fdot2i(qp3, w1q[r].w, a);
            sH[tl + t][r * 64 + lane] = (_Float16)fmaxf(a, 0.0f);
        }
    }

    __syncthreads();   // barrier 3: sH complete

    // ---- ffn2 GEMM: 16x64x256, B=bfrag, waves 4..7, 8 MFMA ----
    if (wv >= 4) {
        f32x4 cacc = {0.0f, 0.0f, 0.0f, 0.0f};
#pragma unroll
        for (int ks = 0; ks < 8; ++ks) {
            f16x8 af = *(const f16x8*)&sH[col][ks * 32 + kg * 8];
            cacc = __builtin_amdgcn_mfma_f32_16x16x32_f16(af, bfrag[ks], cacc, 0, 0, 0);
        }
#pragma unroll
        for (int r = 0; r < 4; ++r)
            sO[kg * 4 + r][(wv - 4) * 16 + col] = cacc[r];
    }

    __syncthreads();   // barrier 4: sO complete

    // ---- out = LN(y + ffn2 + b2) ----
#pragma unroll
    for (int t = 0; t < 2; ++t) {
        float v = y[t] + b2L + sO[tl + t][lane];
        float s = v, s2 = v * v;
        wave_sum2(s, s2);
        float m   = s * 0.015625f;
        float var = s2 * 0.015625f - m * m;
        out[(tok0 + t) * 64 + lane] = (v - m) * rsqrtf(var + 1e-5f) * g2L + be2L;
    }
}

extern "C" void kernel_launch(void* const* d_in, const int* in_sizes, int n_in,
                              void* d_out, int out_size, void* d_ws, size_t ws_size,
                              hipStream_t stream)
{
    const float* x   = (const float*)d_in[0];
    const float* at  = (const float*)d_in[1];
    const float* Wc  = (const float*)d_in[2];
    const float* bcp = (const float*)d_in[3];
    const float* g1  = (const float*)d_in[4];
    const float* be1 = (const float*)d_in[5];
    const float* ft  = (const float*)d_in[6];
    const float* W1  = (const float*)d_in[7];
    const float* b1  = (const float*)d_in[8];
    const float* W2  = (const float*)d_in[9];
    const float* b2  = (const float*)d_in[10];
    const float* g2  = (const float*)d_in[11];
    const float* be2 = (const float*)d_in[12];
    float* out = (float*)d_out;

    // 4096 tokens = 256 blocks x 8 waves x 2 tokens; single dispatch,
    // 1 block/CU, ~23 KB LDS, 4 barriers, B-operands prefetched to registers.
    qtb_fused11<<<256, 512, 0, stream>>>(x, at, Wc, bcp, g1, be1, ft,
                                         W1, b1, W2, b2, g2, be2, out);
}